// Round 1
// baseline (952.576 us; speedup 1.0000x reference)
//
#include <hip/hip_runtime.h>

#define BN 8
#define NN 512
#define FIN 128
#define FOUT 64
#define ALPHA 0.2f

typedef float f32x4 __attribute__((ext_vector_type(4)));

// Kernel 1: Wh[b,n,o] = sum_i h[b,n,i] * W[i,o]; e_i[bn] = Wh·a_i; e_j[bn] = Wh·a_j
__global__ __launch_bounds__(64) void wh_kernel(
    const float* __restrict__ h, const float* __restrict__ W,
    const float* __restrict__ a,
    float* __restrict__ Wh, float* __restrict__ e_i, float* __restrict__ e_j) {
    int bn = blockIdx.x;          // 0..4095
    int o  = threadIdx.x;         // 0..63
    __shared__ float hrow[FIN];
    hrow[o]      = h[bn * FIN + o];
    hrow[o + 64] = h[bn * FIN + 64 + o];
    __syncthreads();
    float acc = 0.f;
#pragma unroll 8
    for (int i = 0; i < FIN; ++i)
        acc = fmaf(hrow[i], W[i * FOUT + o], acc);   // W reads coalesced, L1-resident
    Wh[bn * FOUT + o] = acc;
    float pi = acc * a[o];
    float pj = acc * a[FOUT + o];
#pragma unroll
    for (int off = 32; off >= 1; off >>= 1) {
        pi += __shfl_xor(pi, off, 64);
        pj += __shfl_xor(pj, off, 64);
    }
    if (o == 0) { e_i[bn] = pi; e_j[bn] = pj; }
}

// Kernel 2: per (b,i): s_j = leaky(e_i + e_j[j] + a_e * (edge[b,i,j,:]·U)),
// softmax over j, out[b,i,:] = sum_j p_j * Wh[b,j,:]
//
// Stage 1 is thread-per-j: no cross-lane shuffles, no exec-masked LDS writes.
// Stage 3 uses float4 Wh reads (4x fewer vmem/ds instructions than scalar).
__global__ __launch_bounds__(256, 4) void attn_kernel(
    const float* __restrict__ edge, const float* __restrict__ U,
    const float* __restrict__ a, const float* __restrict__ Wh,
    const float* __restrict__ e_i, const float* __restrict__ e_j,
    float* __restrict__ out) {
    int bi   = blockIdx.x;        // b*NN + i
    int b    = bi >> 9;
    int tid  = threadIdx.x;
    int lane = tid & 63;
    int wave = tid >> 6;

    __shared__ f32x4 Uf4[16];          // U broadcast source (64 floats)
    __shared__ float s_lds[NN];        // scores -> softmax probs
    __shared__ float red[8];
    __shared__ float accbuf[4][FOUT];

    if (tid < 16) Uf4[tid] = ((const f32x4*)U)[tid];
    float a_e = a[2 * FOUT];
    float eiv = e_i[bi];
    float ej0 = e_j[(b << 9) + tid];         // coalesced, L2-resident (16 KB total)
    float ej1 = e_j[(b << 9) + 256 + tid];
    __syncthreads();

    // ---- Stage 1: thread t computes scores for j = t and j = t + 256 ----
    // Lane stride is 256 B; each 64 B line is fully consumed across the k-unroll (L1).
    const f32x4* r0 = (const f32x4*)(edge + (size_t)bi * (NN * FOUT)) + tid * 16;
    const f32x4* r1 = r0 + 256 * 16;
    f32x4 acc0 = {0.f, 0.f, 0.f, 0.f};
    f32x4 acc1 = {0.f, 0.f, 0.f, 0.f};
#pragma unroll
    for (int k = 0; k < 16; ++k) {
        f32x4 u  = Uf4[k];                          // ds_read_b128, same-addr broadcast
        f32x4 x0 = __builtin_nontemporal_load(&r0[k]);  // streaming: don't evict Wh from L2
        f32x4 x1 = __builtin_nontemporal_load(&r1[k]);
        acc0 += x0 * u;
        acc1 += x1 * u;
    }
    float p0 = (acc0.x + acc0.y) + (acc0.z + acc0.w);
    float p1 = (acc1.x + acc1.y) + (acc1.z + acc1.w);
    float s0 = eiv + ej0 + a_e * p0;
    float s1 = eiv + ej1 + a_e * p1;
    s_lds[tid]       = (s0 >= 0.f) ? s0 : (ALPHA * s0);
    s_lds[tid + 256] = (s1 >= 0.f) ? s1 : (ALPHA * s1);
    __syncthreads();

    // ---- Stage 2: softmax over 512 values ----
    float m = fmaxf(s_lds[tid], s_lds[tid + 256]);
#pragma unroll
    for (int off = 32; off >= 1; off >>= 1) m = fmaxf(m, __shfl_xor(m, off, 64));
    if (lane == 0) red[wave] = m;
    __syncthreads();
    m = fmaxf(fmaxf(red[0], red[1]), fmaxf(red[2], red[3]));
    float v0 = expf(s_lds[tid] - m);
    float v1 = expf(s_lds[tid + 256] - m);
    float ssum = v0 + v1;
    s_lds[tid]       = v0;           // each location touched by exactly one thread
    s_lds[tid + 256] = v1;
#pragma unroll
    for (int off = 32; off >= 1; off >>= 1) ssum += __shfl_xor(ssum, off, 64);
    if (lane == 0) red[4 + wave] = ssum;
    __syncthreads();
    float inv = 1.0f / (red[4] + red[5] + red[6] + red[7]);

    // ---- Stage 3: out[o] = inv * sum_j p_j * Wh[b,j,o], float4 over o ----
    // Wave w covers j = it*16 + w*4 + jg; 16 lanes x float4 = one 256 B Wh row.
    int o4 = lane & 15;
    int jg = lane >> 4;
    const f32x4* Wh4 = (const f32x4*)(Wh + (((size_t)b) << 9) * FOUT);
    f32x4 acc = {0.f, 0.f, 0.f, 0.f};
#pragma unroll 8
    for (int it = 0; it < 32; ++it) {
        int j = (it << 4) + (wave << 2) + jg;
        float pj = s_lds[j];                       // 4 distinct banks, 16-lane broadcast
        f32x4 w4 = Wh4[(j << 4) + o4];             // 1 KiB contiguous per wave instr, L2-hit
        acc.x = fmaf(pj, w4.x, acc.x);
        acc.y = fmaf(pj, w4.y, acc.y);
        acc.z = fmaf(pj, w4.z, acc.z);
        acc.w = fmaf(pj, w4.w, acc.w);
    }
    // reduce across the 4 j-groups (lane bits 4,5)
    acc.x += __shfl_xor(acc.x, 16, 64); acc.x += __shfl_xor(acc.x, 32, 64);
    acc.y += __shfl_xor(acc.y, 16, 64); acc.y += __shfl_xor(acc.y, 32, 64);
    acc.z += __shfl_xor(acc.z, 16, 64); acc.z += __shfl_xor(acc.z, 32, 64);
    acc.w += __shfl_xor(acc.w, 16, 64); acc.w += __shfl_xor(acc.w, 32, 64);
    if (lane < 16) ((f32x4*)accbuf)[(wave << 4) + o4] = acc;
    __syncthreads();
    if (tid < 64) {
        float r = (accbuf[0][tid] + accbuf[1][tid] + accbuf[2][tid] + accbuf[3][tid]) * inv;
        out[((size_t)bi << 6) + tid] = r;
    }
}

extern "C" void kernel_launch(void* const* d_in, const int* in_sizes, int n_in,
                              void* d_out, int out_size, void* d_ws, size_t ws_size,
                              hipStream_t stream) {
    const float* h    = (const float*)d_in[0];   // (8,512,128)
    const float* edge = (const float*)d_in[1];   // (8,512,512,64)
    const float* W    = (const float*)d_in[2];   // (1,128,64)
    const float* U    = (const float*)d_in[3];   // (1,64)
    const float* a    = (const float*)d_in[4];   // (1,129)
    float* out = (float*)d_out;                  // (8,512,64)

    float* Wh  = (float*)d_ws;                   // 262144 floats
    float* e_i = Wh + BN * NN * FOUT;            // 4096
    float* e_j = e_i + BN * NN;                  // 4096

    wh_kernel<<<BN * NN, 64, 0, stream>>>(h, W, a, Wh, e_i, e_j);
    attn_kernel<<<BN * NN, 256, 0, stream>>>(edge, U, a, Wh, e_i, e_j, out);
}